// Round 4
// baseline (407.357 us; speedup 1.0000x reference)
//
#include <hip/hip_runtime.h>
#include <math.h>

// ---------------- complex helpers ----------------
__device__ inline float2 cmul(float2 a, float2 b){
  return make_float2(a.x*b.x - a.y*b.y, a.x*b.y + a.y*b.x);
}

// u3(th, ph, lam) = [[c, -e^{i lam} s], [e^{i ph} s, e^{i(ph+lam)} c]]
__device__ inline void mk_u3(const float* p, float2& u00, float2& u01, float2& u10, float2& u11){
  float s, c;   sincosf(0.5f*p[0], &s, &c);
  float sl, cl; sincosf(p[1], &sl, &cl);            // ph
  float sm, cm; sincosf(p[2], &sm, &cm);            // lam
  float s2, c2; sincosf(p[1] + p[2], &s2, &c2);     // ph+lam
  u00 = make_float2(c, 0.f);
  u01 = make_float2(-s*cm, -s*sm);
  u10 = make_float2( s*cl,  s*sl);
  u11 = make_float2( c*c2,  c*s2);
}

__device__ inline void pauli2(int t, float2* m){ // 2x2, m[i*2+j]
  if (t == 0){ m[0]=make_float2(1,0); m[1]=make_float2(0,0);  m[2]=make_float2(0,0); m[3]=make_float2(1,0); }
  else if (t == 1){ m[0]=make_float2(0,0); m[1]=make_float2(1,0);  m[2]=make_float2(1,0); m[3]=make_float2(0,0); }
  else if (t == 2){ m[0]=make_float2(0,0); m[1]=make_float2(0,-1); m[2]=make_float2(0,1); m[3]=make_float2(0,0); }
  else            { m[0]=make_float2(1,0); m[1]=make_float2(0,0);  m[2]=make_float2(0,0); m[3]=make_float2(-1,0);}
}

// ---------------- gate program ----------------
// types: 0=U3(w1), 1=ZZ(w1,w2), 2=YY, 3=XX, 4=CU3(ctrl=w1,tgt=w2), 5=PAULI kron wires(0,4), w1/w2 = pauli ids
// poff: <1000 conv, 1000..1999 pool-1000, >=2000 last-2000
struct GSpec { int type; int w1; int w2; int poff; };
#define NG 66
__device__ const GSpec gspec[NG] = {
  {0,0,0,  0},{0,2,0, 33},{1,0,2,  6},{2,0,2,  7},{3,0,2,  8},{0,0,0,  9},{0,2,0, 42},
  {0,1,0, 15},{0,3,0, 48},{1,1,3, 21},{2,1,3, 22},{3,1,3, 23},{0,1,0, 24},{0,3,0, 57},
  {0,4,0, 60},{0,6,0, 93},{1,4,6, 66},{2,4,6, 67},{3,4,6, 68},{0,4,0, 69},{0,6,0,102},
  {0,5,0, 75},{0,7,0,108},{1,5,7, 81},{2,5,7, 82},{3,5,7, 83},{0,5,0, 84},{0,7,0,117},
  {4,1,0,1000},{4,3,2,1003},{4,5,4,1006},{4,7,6,1009},
  {0,0,0,120},{0,2,0,153},{1,0,2,126},{2,0,2,127},{3,0,2,128},{0,0,0,129},{0,2,0,162},
  {0,4,0,180},{0,4,0,183},{0,4,0,186},{0,4,0,189},{0,4,0,192},
  {0,6,0,210},{0,6,0,213},{0,6,0,216},{0,6,0,219},{0,6,0,222},
  {4,2,0,1012},{4,6,4,1015},
  {5,1,0,2000},{5,2,0,2001},{5,3,0,2002},{5,3,1,2003},{5,0,1,2004},
  {5,1,1,2005},{5,2,1,2006},{5,2,2,2007},{5,3,2,2008},{5,0,2,2009},
  {5,1,2,2010},{5,1,3,2011},{5,2,3,2012},{5,3,3,2013},{5,0,3,2014},
};

// ---------------- state-vector gate engine (state + gates in LDS) ----------------
// Wire w maps to bit (7-w) of the 256-index (wire 0 = MSB).
__device__ inline void apply1q(float2* S, int lane, int bit,
                               float2 u00, float2 u01, float2 u10, float2 u11){
  #pragma unroll
  for (int t = 0; t < 2; t++){
    int p  = lane + 64*t;
    int k0 = ((p >> bit) << (bit+1)) | (p & ((1<<bit)-1));
    int k1 = k0 | (1 << bit);
    float2 a = S[k0], b = S[k1];
    float2 na = make_float2(u00.x*a.x - u00.y*a.y + u01.x*b.x - u01.y*b.y,
                            u00.x*a.y + u00.y*a.x + u01.x*b.y + u01.y*b.x);
    float2 nb = make_float2(u10.x*a.x - u10.y*a.y + u11.x*b.x - u11.y*b.y,
                            u10.x*a.y + u10.y*a.x + u11.x*b.y + u11.y*b.x);
    S[k0] = na; S[k1] = nb;
  }
  __syncthreads();
}

__device__ inline void apply2q(float2* S, int lane, int bitA, int bitB, const float2* G){
  int hi = bitA > bitB ? bitA : bitB;
  int lo = bitA ^ bitB ^ hi;
  int t2  = ((lane >> lo) << (lo+1)) | (lane & ((1<<lo)-1));
  int k00 = ((t2   >> hi) << (hi+1)) | (t2   & ((1<<hi)-1));
  int mA = 1 << bitA, mB = 1 << bitB;
  int id[4] = { k00, k00|mB, k00|mA, k00|mA|mB };
  float2 v[4];
  #pragma unroll
  for (int r = 0; r < 4; r++) v[r] = S[id[r]];
  #pragma unroll
  for (int r = 0; r < 4; r++){
    float re = 0.f, im = 0.f;
    #pragma unroll
    for (int c = 0; c < 4; c++){
      float2 g = G[r*4 + c];
      re += g.x*v[c].x - g.y*v[c].y;
      im += g.x*v[c].y + g.y*v[c].x;
    }
    S[id[r]] = make_float2(re, im);
  }
  __syncthreads();
}

// K1 (fused gates+sim): block j simulates basis state e_j; U[k*256+j] = amplitude k.
__global__ __launch_bounds__(64) void kern_sim(const float* __restrict__ conv,
                                               const float* __restrict__ pool,
                                               const float* __restrict__ last,
                                               float2* __restrict__ U){
  __shared__ float2 Gt[NG*16];
  __shared__ float2 S[256];
  const int lane = threadIdx.x;
  const int j = blockIdx.x;

  // build all gate matrices into LDS (lanes 0..63 cover 66 gates)
  for (int g = lane; g < NG; g += 64){
    GSpec sp = gspec[g];
    const float* base;
    if (sp.poff >= 2000)      base = last + (sp.poff - 2000);
    else if (sp.poff >= 1000) base = pool + (sp.poff - 1000);
    else                      base = conv + sp.poff;
    float2 G[16];
    #pragma unroll
    for (int i = 0; i < 16; i++) G[i] = make_float2(0.f, 0.f);
    if (sp.type == 0){
      float2 a,b,c,d; mk_u3(base,a,b,c,d);
      G[0]=a; G[1]=b; G[2]=c; G[3]=d;
    } else if (sp.type == 1){ // ZZ
      float s,co; sincosf(0.5f*base[0], &s, &co);
      G[0]=make_float2(co,-s); G[5]=make_float2(co,s); G[10]=make_float2(co,s); G[15]=make_float2(co,-s);
    } else if (sp.type == 2){ // YY
      float s,co; sincosf(0.5f*base[0], &s, &co);
      G[0]=G[5]=G[10]=G[15]=make_float2(co,0.f);
      G[3]=make_float2(0.f,s); G[6]=make_float2(0.f,-s); G[9]=make_float2(0.f,-s); G[12]=make_float2(0.f,s);
    } else if (sp.type == 3){ // XX
      float s,co; sincosf(0.5f*base[0], &s, &co);
      G[0]=G[5]=G[10]=G[15]=make_float2(co,0.f);
      G[3]=G[6]=G[9]=G[12]=make_float2(0.f,-s);
    } else if (sp.type == 4){ // CU3
      float2 a,b,c,d; mk_u3(base,a,b,c,d);
      G[0]=make_float2(1.f,0.f); G[5]=make_float2(1.f,0.f);
      G[10]=a; G[11]=b; G[14]=c; G[15]=d;
    } else { // PAULI word: G = cos*I - i sin*(A ⊗ B)
      float s,co; sincosf(0.5f*base[0], &s, &co);
      float2 A2[4], B2[4]; pauli2(sp.w1,A2); pauli2(sp.w2,B2);
      #pragma unroll
      for (int i1 = 0; i1 < 2; i1++)
      #pragma unroll
      for (int i2 = 0; i2 < 2; i2++)
      #pragma unroll
      for (int j1 = 0; j1 < 2; j1++)
      #pragma unroll
      for (int j2 = 0; j2 < 2; j2++){
        float2 Pv = cmul(A2[i1*2+j1], B2[i2*2+j2]);
        int rr = i1*2+i2, cc = j1*2+j2;
        G[rr*4+cc] = make_float2((rr==cc ? co : 0.f) + s*Pv.y, -s*Pv.x);
      }
    }
    #pragma unroll
    for (int i = 0; i < 16; i++) Gt[g*16 + i] = G[i];
  }
  #pragma unroll
  for (int t = 0; t < 4; t++){ int k = lane + 64*t; S[k] = make_float2(k==j ? 1.f : 0.f, 0.f); }
  __syncthreads();

  for (int g = 0; g < NG; g++){
    GSpec sp = gspec[g];
    if (sp.type == 0){
      float2 a = Gt[g*16+0], b = Gt[g*16+1], c = Gt[g*16+2], d = Gt[g*16+3];
      apply1q(S, lane, 7 - sp.w1, a, b, c, d);
    } else {
      int bA, bB;
      if (sp.type == 5){ bA = 7; bB = 3; }
      else             { bA = 7 - sp.w1; bB = 7 - sp.w2; }
      apply2q(S, lane, bA, bB, &Gt[g*16]);
    }
  }
  #pragma unroll
  for (int t = 0; t < 4; t++){ int k = lane + 64*t; U[k*256 + j] = S[k]; }
}

// K2: block xm: D[i] = sum_k z_k Re(conj(U_ki) U_k(i^xm)); FWHT over i; store m table.
__global__ __launch_bounds__(256) void kern_m2(const float2* __restrict__ U,
                                               float* __restrict__ mt){
  __shared__ float dsh[256];
  const int xm = blockIdx.x, i = threadIdx.x;
  const int j2 = i ^ xm;
  float acc = 0.f;
  #pragma unroll 4
  for (int k = 0; k < 128; k++){
    float2 ui0 = U[k*256 + i];
    float2 uj0 = U[k*256 + j2];
    float2 ui1 = U[(k+128)*256 + i];
    float2 uj1 = U[(k+128)*256 + j2];
    acc += (ui0.x*uj0.x + ui0.y*uj0.y) - (ui1.x*uj1.x + ui1.y*uj1.y);
  }
  dsh[i] = acc;
  __syncthreads();
  for (int bit = 1; bit < 256; bit <<= 1){
    float mine = dsh[i], other = dsh[i ^ bit];
    __syncthreads();
    dsh[i] = (i & bit) ? (other - mine) : (mine + other);
    __syncthreads();
  }
  if ((i & xm) == 0){
    int idx = 0, pw = 1;
    #pragma unroll
    for (int b2 = 0; b2 < 8; b2++){
      int dg = ((xm >> b2) & 1) ? 1 : (((i >> b2) & 1) ? 2 : 0);
      idx += dg * pw; pw *= 3;
    }
    mt[idx] = dsh[i] * (1.0f/256.0f);
  }
}

// K3: reduced = tanh(x @ fc_w^T + b).
// Max-occupancy layout: grid 2048 x 4 waves = 8192 waves = 32 waves/CU.
// wave = 2 rows x 32 K-lanes; per lane per iter: 1 x float4 + 8 w float4 (w addr
// identical across the two row-halves -> coalesced broadcast). VGPR target <=64.
__global__ __launch_bounds__(256, 8) void kern_gemv(const float* __restrict__ x,
                                                    const float* __restrict__ w,
                                                    const float* __restrict__ b,
                                                    float* __restrict__ red){
  const int wave = threadIdx.x >> 6, lane = threadIdx.x & 63;
  const int rl = lane >> 5, co = lane & 31;
  const int gw = blockIdx.x*4 + wave;          // 0..8191
  const int row = gw*2 + rl;
  const float4* xp = (const float4*)(x + (size_t)row*3072);
  const float4* wp = (const float4*)w;
  float acc[8];
  #pragma unroll
  for (int q = 0; q < 8; q++) acc[q] = 0.f;
  for (int it = 0; it < 24; it++){
    int c = it*32 + co;
    float4 xv = xp[c];
    #pragma unroll
    for (int q = 0; q < 8; q++){
      float4 wv = wp[q*768 + c];
      acc[q] += wv.x*xv.x + wv.y*xv.y + wv.z*xv.z + wv.w*xv.w;
    }
  }
  #pragma unroll
  for (int q = 0; q < 8; q++){
    float v = acc[q];
    v += __shfl_xor(v, 1);
    v += __shfl_xor(v, 2);
    v += __shfl_xor(v, 4);
    v += __shfl_xor(v, 8);
    v += __shfl_xor(v, 16);
    acc[q] = v;
  }
  if (co == 0){
    float4 o0 = make_float4(tanhf(acc[0]+b[0]), tanhf(acc[1]+b[1]),
                            tanhf(acc[2]+b[2]), tanhf(acc[3]+b[3]));
    float4 o1 = make_float4(tanhf(acc[4]+b[4]), tanhf(acc[5]+b[5]),
                            tanhf(acc[6]+b[6]), tanhf(acc[7]+b[7]));
    float4* rp = (float4*)(red + (size_t)row*8);
    rp[0] = o0; rp[1] = o1;
  }
}

// K4: z0[e] = sum over 3^8 Pauli strings m_p * prod t_w; logits = z0*fow + fob.
// Block = 4 waves over the SAME 64 elements, h-loop split across waves; mt in LDS.
__global__ __launch_bounds__(256) void kern_contract(const float* __restrict__ red,
                                                     const float* __restrict__ mt,
                                                     const float* __restrict__ fow,
                                                     const float* __restrict__ fob,
                                                     float* __restrict__ out){
  __shared__ float mtl[9*27*32];
  __shared__ float zsh[4*64];
  const int tid = threadIdx.x;
  for (int idx = tid; idx < 9*27*32; idx += 256){
    int h  = idx / 864;           // 864 = 27*32
    int r  = idx - h*864;
    int mm = r >> 5, l = r & 31;
    mtl[idx] = (l < 27) ? mt[h*729 + mm*27 + l] : 0.f;
  }
  const int wave = tid >> 6, lane = tid & 63;
  const int e = blockIdx.x*64 + lane;
  const float4* rp = (const float4*)(red + (size_t)e*8);
  float4 r0 = rp[0], r1 = rp[1];
  __syncthreads();

  float rr[8] = {r0.x, r0.y, r0.z, r0.w, r1.x, r1.y, r1.z, r1.w};
  float sn[8], cs[8];
  #pragma unroll
  for (int q = 0; q < 8; q++) sincosf(rr[q], &sn[q], &cs[q]);
  // digit d at bit b: 0 -> 1, 1 -> sin(r[7-b]) (X), 2 -> cos(r[7-b]) (Z)
  float f0[3] = {1.f, sn[7], cs[7]};
  float f1[3] = {1.f, sn[6], cs[6]};
  float f2[3] = {1.f, sn[5], cs[5]};
  float g27[32];
  #pragma unroll
  for (int z = 27; z < 32; z++) g27[z] = 0.f;
  #pragma unroll
  for (int d2 = 0; d2 < 3; d2++)
  #pragma unroll
  for (int d1 = 0; d1 < 3; d1++)
  #pragma unroll
  for (int d0 = 0; d0 < 3; d0++)
    g27[9*d2 + 3*d1 + d0] = f2[d2]*f1[d1]*f0[d0];
  float4 glo4[8];
  #pragma unroll
  for (int v = 0; v < 8; v++)
    glo4[v] = make_float4(g27[4*v], g27[4*v+1], g27[4*v+2], g27[4*v+3]);
  float f3[3] = {1.f, sn[4], cs[4]};
  float f4[3] = {1.f, sn[3], cs[3]};
  float f5[3] = {1.f, sn[2], cs[2]};
  float gmid[27];
  #pragma unroll
  for (int d5 = 0; d5 < 3; d5++)
  #pragma unroll
  for (int d4 = 0; d4 < 3; d4++)
  #pragma unroll
  for (int d3 = 0; d3 < 3; d3++)
    gmid[9*d5 + 3*d4 + d3] = f5[d5]*f4[d4]*f3[d3];
  float f6[3] = {1.f, sn[1], cs[1]};
  float f7[3] = {1.f, sn[0], cs[0]};
  float ghi[9];
  #pragma unroll
  for (int d7 = 0; d7 < 3; d7++)
  #pragma unroll
  for (int d6 = 0; d6 < 3; d6++)
    ghi[3*d7 + d6] = f7[d7]*f6[d6];

  // wave h-partition: {0,1,2},{3,4},{5,6},{7,8}
  const int hbeg = (wave==0) ? 0 : (wave==1) ? 3 : (wave==2) ? 5 : 7;
  const int hend = hbeg + ((wave==0) ? 3 : 2);
  float part = 0.f;
  for (int h = hbeg; h < hend; h++){
    float ha = 0.f, hb = 0.f;
    #pragma unroll 3
    for (int mm = 0; mm < 27; mm++){
      const float4* mp = (const float4*)&mtl[(h*27 + mm) << 5];
      float d0 = 0.f, d1 = 0.f;
      #pragma unroll
      for (int v = 0; v < 8; v += 2){
        float4 m0 = mp[v], m1 = mp[v+1];
        d0 += m0.x*glo4[v].x   + m0.y*glo4[v].y   + m0.z*glo4[v].z   + m0.w*glo4[v].w;
        d1 += m1.x*glo4[v+1].x + m1.y*glo4[v+1].y + m1.z*glo4[v+1].z + m1.w*glo4[v+1].w;
      }
      float term = (d0 + d1) * gmid[mm];
      if (mm & 1) hb += term; else ha += term;
    }
    part += (ha + hb) * ghi[h];
  }
  zsh[wave*64 + lane] = part;
  __syncthreads();

  for (int idx = tid; idx < 640; idx += 256){
    int el = idx / 10, c = idx - el*10;
    float z = zsh[el] + zsh[64+el] + zsh[128+el] + zsh[192+el];
    out[((size_t)blockIdx.x*64 + el)*10 + c] = z*fow[c] + fob[c];
  }
}

extern "C" void kernel_launch(void* const* d_in, const int* in_sizes, int n_in,
                              void* d_out, int out_size, void* d_ws, size_t ws_size,
                              hipStream_t stream) {
  (void)in_sizes; (void)n_in; (void)out_size; (void)ws_size;
  const float* x    = (const float*)d_in[0];
  const float* fcw  = (const float*)d_in[1];
  const float* fcb  = (const float*)d_in[2];
  const float* conv = (const float*)d_in[3];
  const float* pool = (const float*)d_in[4];
  const float* last = (const float*)d_in[5];
  const float* fow  = (const float*)d_in[6];
  const float* fob  = (const float*)d_in[7];
  float* out = (float*)d_out;

  char* ws = (char*)d_ws;
  float2* U   = (float2*)ws;                    // 512 KiB
  float*  red = (float*) (ws + 512*1024);       // 512 KiB
  float*  mt  = (float*) (ws + 1024*1024);      // ~26 KiB

  kern_sim     <<<256,  64,  0, stream>>>(conv, pool, last, U);
  kern_m2      <<<256,  256, 0, stream>>>(U, mt);
  kern_gemv    <<<2048, 256, 0, stream>>>(x, fcw, fcb, red);
  kern_contract<<<256,  256, 0, stream>>>(red, mt, fow, fob, out);
}

// Round 5
// 372.238 us; speedup vs baseline: 1.0943x; 1.0943x over previous
//
#include <hip/hip_runtime.h>
#include <math.h>

// ---------------- complex helpers ----------------
__device__ inline float2 cmul(float2 a, float2 b){
  return make_float2(a.x*b.x - a.y*b.y, a.x*b.y + a.y*b.x);
}

// u3(th, ph, lam) = [[c, -e^{i lam} s], [e^{i ph} s, e^{i(ph+lam)} c]]
__device__ inline void mk_u3(const float* p, float2& u00, float2& u01, float2& u10, float2& u11){
  float s, c;   sincosf(0.5f*p[0], &s, &c);
  float sl, cl; sincosf(p[1], &sl, &cl);            // ph
  float sm, cm; sincosf(p[2], &sm, &cm);            // lam
  float s2, c2; sincosf(p[1] + p[2], &s2, &c2);     // ph+lam
  u00 = make_float2(c, 0.f);
  u01 = make_float2(-s*cm, -s*sm);
  u10 = make_float2( s*cl,  s*sl);
  u11 = make_float2( c*c2,  c*s2);
}

__device__ inline void pauli2(int t, float2* m){ // 2x2, m[i*2+j]
  if (t == 0){ m[0]=make_float2(1,0); m[1]=make_float2(0,0);  m[2]=make_float2(0,0); m[3]=make_float2(1,0); }
  else if (t == 1){ m[0]=make_float2(0,0); m[1]=make_float2(1,0);  m[2]=make_float2(1,0); m[3]=make_float2(0,0); }
  else if (t == 2){ m[0]=make_float2(0,0); m[1]=make_float2(0,-1); m[2]=make_float2(0,1); m[3]=make_float2(0,0); }
  else            { m[0]=make_float2(1,0); m[1]=make_float2(0,0);  m[2]=make_float2(0,0); m[3]=make_float2(-1,0);}
}

// ---------------- gate program ----------------
// types: 0=U3(w1), 1=ZZ(w1,w2), 2=YY, 3=XX, 4=CU3(ctrl=w1,tgt=w2), 5=PAULI kron wires(0,4), w1/w2 = pauli ids
// poff: <1000 conv, 1000..1999 pool-1000, >=2000 last-2000
struct GSpec { int type; int w1; int w2; int poff; };
#define NG 66
__device__ const GSpec gspec[NG] = {
  {0,0,0,  0},{0,2,0, 33},{1,0,2,  6},{2,0,2,  7},{3,0,2,  8},{0,0,0,  9},{0,2,0, 42},
  {0,1,0, 15},{0,3,0, 48},{1,1,3, 21},{2,1,3, 22},{3,1,3, 23},{0,1,0, 24},{0,3,0, 57},
  {0,4,0, 60},{0,6,0, 93},{1,4,6, 66},{2,4,6, 67},{3,4,6, 68},{0,4,0, 69},{0,6,0,102},
  {0,5,0, 75},{0,7,0,108},{1,5,7, 81},{2,5,7, 82},{3,5,7, 83},{0,5,0, 84},{0,7,0,117},
  {4,1,0,1000},{4,3,2,1003},{4,5,4,1006},{4,7,6,1009},
  {0,0,0,120},{0,2,0,153},{1,0,2,126},{2,0,2,127},{3,0,2,128},{0,0,0,129},{0,2,0,162},
  {0,4,0,180},{0,4,0,183},{0,4,0,186},{0,4,0,189},{0,4,0,192},
  {0,6,0,210},{0,6,0,213},{0,6,0,216},{0,6,0,219},{0,6,0,222},
  {4,2,0,1012},{4,6,4,1015},
  {5,1,0,2000},{5,2,0,2001},{5,3,0,2002},{5,3,1,2003},{5,0,1,2004},
  {5,1,1,2005},{5,2,1,2006},{5,2,2,2007},{5,3,2,2008},{5,0,2,2009},
  {5,1,2,2010},{5,1,3,2011},{5,2,3,2012},{5,3,3,2013},{5,0,3,2014},
};

// ---------------- state-vector gate engine (state + gates in LDS) ----------------
// Wire w maps to bit (7-w) of the 256-index (wire 0 = MSB).
__device__ inline void apply1q(float2* S, int lane, int bit,
                               float2 u00, float2 u01, float2 u10, float2 u11){
  #pragma unroll
  for (int t = 0; t < 2; t++){
    int p  = lane + 64*t;
    int k0 = ((p >> bit) << (bit+1)) | (p & ((1<<bit)-1));
    int k1 = k0 | (1 << bit);
    float2 a = S[k0], b = S[k1];
    float2 na = make_float2(u00.x*a.x - u00.y*a.y + u01.x*b.x - u01.y*b.y,
                            u00.x*a.y + u00.y*a.x + u01.x*b.y + u01.y*b.x);
    float2 nb = make_float2(u10.x*a.x - u10.y*a.y + u11.x*b.x - u11.y*b.y,
                            u10.x*a.y + u10.y*a.x + u11.x*b.y + u11.y*b.x);
    S[k0] = na; S[k1] = nb;
  }
  __syncthreads();
}

__device__ inline void apply2q(float2* S, int lane, int bitA, int bitB, const float2* G){
  int hi = bitA > bitB ? bitA : bitB;
  int lo = bitA ^ bitB ^ hi;
  int t2  = ((lane >> lo) << (lo+1)) | (lane & ((1<<lo)-1));
  int k00 = ((t2   >> hi) << (hi+1)) | (t2   & ((1<<hi)-1));
  int mA = 1 << bitA, mB = 1 << bitB;
  int id[4] = { k00, k00|mB, k00|mA, k00|mA|mB };
  float2 v[4];
  #pragma unroll
  for (int r = 0; r < 4; r++) v[r] = S[id[r]];
  #pragma unroll
  for (int r = 0; r < 4; r++){
    float re = 0.f, im = 0.f;
    #pragma unroll
    for (int c = 0; c < 4; c++){
      float2 g = G[r*4 + c];
      re += g.x*v[c].x - g.y*v[c].y;
      im += g.x*v[c].y + g.y*v[c].x;
    }
    S[id[r]] = make_float2(re, im);
  }
  __syncthreads();
}

// K1 (fused gates+sim): block j simulates basis state e_j; U[k*256+j] = amplitude k.
__global__ __launch_bounds__(64) void kern_sim(const float* __restrict__ conv,
                                               const float* __restrict__ pool,
                                               const float* __restrict__ last,
                                               float2* __restrict__ U){
  __shared__ float2 Gt[NG*16];
  __shared__ float2 S[256];
  const int lane = threadIdx.x;
  const int j = blockIdx.x;

  // build all gate matrices into LDS (lanes 0..63 cover 66 gates)
  for (int g = lane; g < NG; g += 64){
    GSpec sp = gspec[g];
    const float* base;
    if (sp.poff >= 2000)      base = last + (sp.poff - 2000);
    else if (sp.poff >= 1000) base = pool + (sp.poff - 1000);
    else                      base = conv + sp.poff;
    float2 G[16];
    #pragma unroll
    for (int i = 0; i < 16; i++) G[i] = make_float2(0.f, 0.f);
    if (sp.type == 0){
      float2 a,b,c,d; mk_u3(base,a,b,c,d);
      G[0]=a; G[1]=b; G[2]=c; G[3]=d;
    } else if (sp.type == 1){ // ZZ
      float s,co; sincosf(0.5f*base[0], &s, &co);
      G[0]=make_float2(co,-s); G[5]=make_float2(co,s); G[10]=make_float2(co,s); G[15]=make_float2(co,-s);
    } else if (sp.type == 2){ // YY
      float s,co; sincosf(0.5f*base[0], &s, &co);
      G[0]=G[5]=G[10]=G[15]=make_float2(co,0.f);
      G[3]=make_float2(0.f,s); G[6]=make_float2(0.f,-s); G[9]=make_float2(0.f,-s); G[12]=make_float2(0.f,s);
    } else if (sp.type == 3){ // XX
      float s,co; sincosf(0.5f*base[0], &s, &co);
      G[0]=G[5]=G[10]=G[15]=make_float2(co,0.f);
      G[3]=G[6]=G[9]=G[12]=make_float2(0.f,-s);
    } else if (sp.type == 4){ // CU3
      float2 a,b,c,d; mk_u3(base,a,b,c,d);
      G[0]=make_float2(1.f,0.f); G[5]=make_float2(1.f,0.f);
      G[10]=a; G[11]=b; G[14]=c; G[15]=d;
    } else { // PAULI word: G = cos*I - i sin*(A ⊗ B)
      float s,co; sincosf(0.5f*base[0], &s, &co);
      float2 A2[4], B2[4]; pauli2(sp.w1,A2); pauli2(sp.w2,B2);
      #pragma unroll
      for (int i1 = 0; i1 < 2; i1++)
      #pragma unroll
      for (int i2 = 0; i2 < 2; i2++)
      #pragma unroll
      for (int j1 = 0; j1 < 2; j1++)
      #pragma unroll
      for (int j2 = 0; j2 < 2; j2++){
        float2 Pv = cmul(A2[i1*2+j1], B2[i2*2+j2]);
        int rr = i1*2+i2, cc = j1*2+j2;
        G[rr*4+cc] = make_float2((rr==cc ? co : 0.f) + s*Pv.y, -s*Pv.x);
      }
    }
    #pragma unroll
    for (int i = 0; i < 16; i++) Gt[g*16 + i] = G[i];
  }
  #pragma unroll
  for (int t = 0; t < 4; t++){ int k = lane + 64*t; S[k] = make_float2(k==j ? 1.f : 0.f, 0.f); }
  __syncthreads();

  for (int g = 0; g < NG; g++){
    GSpec sp = gspec[g];
    if (sp.type == 0){
      float2 a = Gt[g*16+0], b = Gt[g*16+1], c = Gt[g*16+2], d = Gt[g*16+3];
      apply1q(S, lane, 7 - sp.w1, a, b, c, d);
    } else {
      int bA, bB;
      if (sp.type == 5){ bA = 7; bB = 3; }
      else             { bA = 7 - sp.w1; bB = 7 - sp.w2; }
      apply2q(S, lane, bA, bB, &Gt[g*16]);
    }
  }
  #pragma unroll
  for (int t = 0; t < 4; t++){ int k = lane + 64*t; U[k*256 + j] = S[k]; }
}

// K2: block xm: D[i] = sum_k z_k Re(conj(U_ki) U_k(i^xm)); FWHT over i; store m table.
__global__ __launch_bounds__(256) void kern_m2(const float2* __restrict__ U,
                                               float* __restrict__ mt){
  __shared__ float dsh[256];
  const int xm = blockIdx.x, i = threadIdx.x;
  const int j2 = i ^ xm;
  float acc = 0.f;
  #pragma unroll 4
  for (int k = 0; k < 128; k++){
    float2 ui0 = U[k*256 + i];
    float2 uj0 = U[k*256 + j2];
    float2 ui1 = U[(k+128)*256 + i];
    float2 uj1 = U[(k+128)*256 + j2];
    acc += (ui0.x*uj0.x + ui0.y*uj0.y) - (ui1.x*uj1.x + ui1.y*uj1.y);
  }
  dsh[i] = acc;
  __syncthreads();
  for (int bit = 1; bit < 256; bit <<= 1){
    float mine = dsh[i], other = dsh[i ^ bit];
    __syncthreads();
    dsh[i] = (i & bit) ? (other - mine) : (mine + other);
    __syncthreads();
  }
  if ((i & xm) == 0){
    int idx = 0, pw = 1;
    #pragma unroll
    for (int b2 = 0; b2 < 8; b2++){
      int dg = ((xm >> b2) & 1) ? 1 : (((i >> b2) & 1) ? 2 : 0);
      idx += dg * pw; pw *= 3;
    }
    mt[idx] = dsh[i] * (1.0f/256.0f);
  }
}

// K3: reduced = tanh(x @ fc_w^T + b).
// w staged in LDS (two 48 KB K-tiles) -> zero global w traffic in the hot loop.
// Block = 256 threads = 4 waves; wave = 2 rows x 32 K-lanes; block covers 8 rows.
__global__ __launch_bounds__(256) void kern_gemv(const float* __restrict__ x,
                                                 const float* __restrict__ w,
                                                 const float* __restrict__ b,
                                                 float* __restrict__ red){
  __shared__ float4 wl[3072];                // 48 KiB: one K-half of w, [8][384] float4
  const int tid = threadIdx.x;
  const int wave = tid >> 6, lane = tid & 63;
  const int rl = lane >> 5, co = lane & 31;
  const int row = blockIdx.x*8 + wave*2 + rl;
  const float4* xp = (const float4*)(x + (size_t)row*3072);
  const float4* wp = (const float4*)w;       // [8][768] float4
  float acc[8];
  #pragma unroll
  for (int q = 0; q < 8; q++) acc[q] = 0.f;

  #pragma unroll
  for (int half = 0; half < 2; half++){
    // stage K-tile: wl[q*384 + cc] = wp[q*768 + half*384 + cc]
    __syncthreads();                          // previous tile fully consumed
    #pragma unroll
    for (int i = 0; i < 12; i++){
      int idx = tid + 256*i;                  // 0..3071
      int q = idx / 384, cc = idx - q*384;
      wl[idx] = wp[q*768 + half*384 + cc];
    }
    __syncthreads();
    #pragma unroll 2
    for (int it = 0; it < 12; it++){
      int cl = it*32 + co;                    // 0..383 within tile
      float4 xv = xp[half*384 + cl];
      #pragma unroll
      for (int q = 0; q < 8; q++){
        float4 wv = wl[q*384 + cl];
        acc[q] += wv.x*xv.x + wv.y*xv.y + wv.z*xv.z + wv.w*xv.w;
      }
    }
  }

  #pragma unroll
  for (int q = 0; q < 8; q++){
    float v = acc[q];
    v += __shfl_xor(v, 1);
    v += __shfl_xor(v, 2);
    v += __shfl_xor(v, 4);
    v += __shfl_xor(v, 8);
    v += __shfl_xor(v, 16);                   // stays within the 32-lane rl half
    acc[q] = v;
  }
  if (co == 0){
    float4 o0 = make_float4(tanhf(acc[0]+b[0]), tanhf(acc[1]+b[1]),
                            tanhf(acc[2]+b[2]), tanhf(acc[3]+b[3]));
    float4 o1 = make_float4(tanhf(acc[4]+b[4]), tanhf(acc[5]+b[5]),
                            tanhf(acc[6]+b[6]), tanhf(acc[7]+b[7]));
    float4* rp = (float4*)(red + (size_t)row*8);
    rp[0] = o0; rp[1] = o1;
  }
}

// K4: z0[e] = sum over 3^8 Pauli strings m_p * prod t_w; logits = z0*fow + fob.
// Block = 4 waves over the SAME 64 elements, h-loop split across waves; mt in LDS.
__global__ __launch_bounds__(256) void kern_contract(const float* __restrict__ red,
                                                     const float* __restrict__ mt,
                                                     const float* __restrict__ fow,
                                                     const float* __restrict__ fob,
                                                     float* __restrict__ out){
  __shared__ float mtl[9*27*32];
  __shared__ float zsh[4*64];
  const int tid = threadIdx.x;
  for (int idx = tid; idx < 9*27*32; idx += 256){
    int h  = idx / 864;           // 864 = 27*32
    int r  = idx - h*864;
    int mm = r >> 5, l = r & 31;
    mtl[idx] = (l < 27) ? mt[h*729 + mm*27 + l] : 0.f;
  }
  const int wave = tid >> 6, lane = tid & 63;
  const int e = blockIdx.x*64 + lane;
  const float4* rp = (const float4*)(red + (size_t)e*8);
  float4 r0 = rp[0], r1 = rp[1];
  __syncthreads();

  float rr[8] = {r0.x, r0.y, r0.z, r0.w, r1.x, r1.y, r1.z, r1.w};
  float sn[8], cs[8];
  #pragma unroll
  for (int q = 0; q < 8; q++) sincosf(rr[q], &sn[q], &cs[q]);
  // digit d at bit b: 0 -> 1, 1 -> sin(r[7-b]) (X), 2 -> cos(r[7-b]) (Z)
  float f0[3] = {1.f, sn[7], cs[7]};
  float f1[3] = {1.f, sn[6], cs[6]};
  float f2[3] = {1.f, sn[5], cs[5]};
  float g27[32];
  #pragma unroll
  for (int z = 27; z < 32; z++) g27[z] = 0.f;
  #pragma unroll
  for (int d2 = 0; d2 < 3; d2++)
  #pragma unroll
  for (int d1 = 0; d1 < 3; d1++)
  #pragma unroll
  for (int d0 = 0; d0 < 3; d0++)
    g27[9*d2 + 3*d1 + d0] = f2[d2]*f1[d1]*f0[d0];
  float4 glo4[8];
  #pragma unroll
  for (int v = 0; v < 8; v++)
    glo4[v] = make_float4(g27[4*v], g27[4*v+1], g27[4*v+2], g27[4*v+3]);
  float f3[3] = {1.f, sn[4], cs[4]};
  float f4[3] = {1.f, sn[3], cs[3]};
  float f5[3] = {1.f, sn[2], cs[2]};
  float gmid[27];
  #pragma unroll
  for (int d5 = 0; d5 < 3; d5++)
  #pragma unroll
  for (int d4 = 0; d4 < 3; d4++)
  #pragma unroll
  for (int d3 = 0; d3 < 3; d3++)
    gmid[9*d5 + 3*d4 + d3] = f5[d5]*f4[d4]*f3[d3];
  float f6[3] = {1.f, sn[1], cs[1]};
  float f7[3] = {1.f, sn[0], cs[0]};
  float ghi[9];
  #pragma unroll
  for (int d7 = 0; d7 < 3; d7++)
  #pragma unroll
  for (int d6 = 0; d6 < 3; d6++)
    ghi[3*d7 + d6] = f7[d7]*f6[d6];

  // wave h-partition: {0,1,2},{3,4},{5,6},{7,8}
  const int hbeg = (wave==0) ? 0 : (wave==1) ? 3 : (wave==2) ? 5 : 7;
  const int hend = hbeg + ((wave==0) ? 3 : 2);
  float part = 0.f;
  for (int h = hbeg; h < hend; h++){
    float ha = 0.f, hb = 0.f;
    #pragma unroll 3
    for (int mm = 0; mm < 27; mm++){
      const float4* mp = (const float4*)&mtl[(h*27 + mm) << 5];
      float d0 = 0.f, d1 = 0.f;
      #pragma unroll
      for (int v = 0; v < 8; v += 2){
        float4 m0 = mp[v], m1 = mp[v+1];
        d0 += m0.x*glo4[v].x   + m0.y*glo4[v].y   + m0.z*glo4[v].z   + m0.w*glo4[v].w;
        d1 += m1.x*glo4[v+1].x + m1.y*glo4[v+1].y + m1.z*glo4[v+1].z + m1.w*glo4[v+1].w;
      }
      float term = (d0 + d1) * gmid[mm];
      if (mm & 1) hb += term; else ha += term;
    }
    part += (ha + hb) * ghi[h];
  }
  zsh[wave*64 + lane] = part;
  __syncthreads();

  for (int idx = tid; idx < 640; idx += 256){
    int el = idx / 10, c = idx - el*10;
    float z = zsh[el] + zsh[64+el] + zsh[128+el] + zsh[192+el];
    out[((size_t)blockIdx.x*64 + el)*10 + c] = z*fow[c] + fob[c];
  }
}

extern "C" void kernel_launch(void* const* d_in, const int* in_sizes, int n_in,
                              void* d_out, int out_size, void* d_ws, size_t ws_size,
                              hipStream_t stream) {
  (void)in_sizes; (void)n_in; (void)out_size; (void)ws_size;
  const float* x    = (const float*)d_in[0];
  const float* fcw  = (const float*)d_in[1];
  const float* fcb  = (const float*)d_in[2];
  const float* conv = (const float*)d_in[3];
  const float* pool = (const float*)d_in[4];
  const float* last = (const float*)d_in[5];
  const float* fow  = (const float*)d_in[6];
  const float* fob  = (const float*)d_in[7];
  float* out = (float*)d_out;

  char* ws = (char*)d_ws;
  float2* U   = (float2*)ws;                    // 512 KiB
  float*  red = (float*) (ws + 512*1024);       // 512 KiB
  float*  mt  = (float*) (ws + 1024*1024);      // ~26 KiB

  kern_sim     <<<256,  64,  0, stream>>>(conv, pool, last, U);
  kern_m2      <<<256,  256, 0, stream>>>(U, mt);
  kern_gemv    <<<2048, 256, 0, stream>>>(x, fcw, fcb, red);
  kern_contract<<<256,  256, 0, stream>>>(red, mt, fow, fob, out);
}